// Round 1
// baseline (206.012 us; speedup 1.0000x reference)
//
#include <hip/hip_runtime.h>
#include <hip/hip_bf16.h>

// Problem constants (fixed by setup_inputs)
#define BSZ  4096
#define NTOT 8192      // bsz * n_views
#define D    512
#define NCLS 100
#define INV_T 14.285714285714286f   // 1/0.07

typedef __attribute__((ext_vector_type(4))) float f32x4;
typedef __attribute__((ext_vector_type(8))) short bf16x8;

// round-to-nearest-even fp32 -> bf16
__device__ __forceinline__ unsigned short f2bf(float f) {
  union { float f; unsigned int u; } v; v.f = f;
  unsigned int u = v.u;
  u += 0x7fffu + ((u >> 16) & 1u);
  return (unsigned short)(u >> 16);
}

// Kernel 1: build bf16 contrast matrix X[N][D] with view-swap layout,
// zero row accumulators. contrast[v*BSZ+b][k] = feat[b][v][k].
__global__ void prep_kernel(const float* __restrict__ feat,
                            unsigned short* __restrict__ X,
                            float* __restrict__ rowA,
                            unsigned int* __restrict__ rowM) {
  int idx = blockIdx.x * blockDim.x + threadIdx.x;
  int stride = gridDim.x * blockDim.x;
  for (int e = idx; e < NTOT * D; e += stride) {
    int row = e >> 9;           // e / 512
    int k = e & 511;
    int v = row >> 12;          // row / 4096
    int b = row & 4095;
    X[e] = f2bf(feat[(((b << 1) + v) << 9) + k]);
  }
  for (int e = idx; e < NTOT; e += stride) { rowA[e] = 0.f; rowM[e] = 0u; }
}

// Kernel 2: fused Gram + epilogue.
// C = X X^T (bf16 MFMA, fp32 acc). Per element: sim = c^2/T;
// signed sum (sign = 0 on diag, -1 same label, +1 diff label) and max per row.
#define BM 128
#define BN 128
#define BK 32

__global__ __launch_bounds__(256) void gram_kernel(
    const unsigned short* __restrict__ X,
    const int* __restrict__ labels,
    float* __restrict__ rowA,
    unsigned int* __restrict__ rowM) {
  __shared__ __align__(16) unsigned short As[BM * BK];  // [128][32] bf16, linear
  __shared__ __align__(16) unsigned short Bs[BN * BK];
  __shared__ int labI[BM];
  __shared__ int labJ[BN];

  const int tid = threadIdx.x;
  const int rowBase = blockIdx.y * BM;
  const int colBase = blockIdx.x * BN;

  if (tid < BM) labI[tid] = labels[(rowBase + tid) & (BSZ - 1)];
  else          labJ[tid - BM] = labels[(colBase + tid - BM) & (BSZ - 1)];

  const int lane = tid & 63;
  const int wid  = tid >> 6;   // 4 waves: 2x2 wave grid, each owns 64x64
  const int wr   = wid >> 1;
  const int wc   = wid & 1;
  const int l15  = lane & 15;
  const int lg   = lane >> 4;

  f32x4 acc[4][4] = {};        // 4x4 fragments of 16x16 per wave

  for (int k0 = 0; k0 < D; k0 += BK) {
    __syncthreads();           // protect LDS from previous iteration's readers
    // Stage A and B tiles (8192 B each) via global_load_lds width-16.
    // Per round: 4 waves x 64 lanes x 16 B = 4096 B; 2 rounds per tile.
    // LDS dest is wave-uniform base + lane*16 (linear layout required).
#pragma unroll
    for (int r = 0; r < 2; ++r) {
      int flat = r * 4096 + wid * 1024 + lane * 16;   // byte offset in tile
      int row = flat >> 6;                            // 64 B per row of 32 bf16
      int kb = flat & 63;
      const unsigned short* srcA = X + (size_t)(rowBase + row) * D + k0 + (kb >> 1);
      const unsigned short* srcB = X + (size_t)(colBase + row) * D + k0 + (kb >> 1);
      __builtin_amdgcn_global_load_lds(
          (const __attribute__((address_space(1))) void*)srcA,
          (__attribute__((address_space(3))) void*)((char*)As + r * 4096 + wid * 1024),
          16, 0, 0);
      __builtin_amdgcn_global_load_lds(
          (const __attribute__((address_space(1))) void*)srcB,
          (__attribute__((address_space(3))) void*)((char*)Bs + r * 4096 + wid * 1024),
          16, 0, 0);
    }
    __syncthreads();           // staging complete (drains vmcnt)

    bf16x8 a[4], b[4];
#pragma unroll
    for (int mi = 0; mi < 4; ++mi)
      a[mi] = *(const bf16x8*)(As + (wr * 64 + mi * 16 + l15) * BK + lg * 8);
#pragma unroll
    for (int nj = 0; nj < 4; ++nj)
      b[nj] = *(const bf16x8*)(Bs + (wc * 64 + nj * 16 + l15) * BK + lg * 8);
#pragma unroll
    for (int mi = 0; mi < 4; ++mi)
#pragma unroll
      for (int nj = 0; nj < 4; ++nj)
        acc[mi][nj] = __builtin_amdgcn_mfma_f32_16x16x32_bf16(
            a[mi], b[nj], acc[mi][nj], 0, 0, 0);
  }

  // Epilogue: C/D mapping (16x16x32): col = lane&15, row = (lane>>4)*4 + reg.
#pragma unroll
  for (int mi = 0; mi < 4; ++mi) {
#pragma unroll
    for (int reg = 0; reg < 4; ++reg) {
      int rit = wr * 64 + mi * 16 + lg * 4 + reg;   // row in tile
      int i = rowBase + rit;
      int li = labI[rit];
      float s = 0.f;
      float mx = 0.f;
#pragma unroll
      for (int nj = 0; nj < 4; ++nj) {
        int cit = wc * 64 + nj * 16 + l15;          // col in tile
        int j = colBase + cit;
        float g = acc[mi][nj][reg];
        float sim = g * g * INV_T;
        mx = fmaxf(mx, sim);                        // max INCLUDES diagonal
        float sgn = (i == j) ? 0.f : ((li == labJ[cit]) ? -1.f : 1.f);
        s = fmaf(sim, sgn, s);
      }
      // reduce across the 16 lanes holding this row's 16 columns
#pragma unroll
      for (int d = 1; d < 16; d <<= 1) {
        s += __shfl_xor(s, d, 64);
        mx = fmaxf(mx, __shfl_xor(mx, d, 64));
      }
      if (l15 == 0) {
        atomicAdd(&rowA[i], s);
        atomicMax(&rowM[i], __float_as_uint(mx));   // sim >= 0: uint-order ok
      }
    }
  }
}

// Kernel 3: label histogram + final reduction (double accum: fp32 sum of
// 8192 values of ~3e10 magnitude would random-walk ~7e8, at threshold).
__global__ void finalize_kernel(const int* __restrict__ labels,
                                const float* __restrict__ rowA,
                                const unsigned int* __restrict__ rowM,
                                float* __restrict__ out) {
  __shared__ int hist[NCLS];
  __shared__ double wsum[4];
  int tid = threadIdx.x;
  for (int c = tid; c < NCLS; c += 256) hist[c] = 0;
  __syncthreads();
  for (int b = tid; b < BSZ; b += 256) atomicAdd(&hist[labels[b]], 1);
  __syncthreads();
  double acc = 0.0;
  for (int i = tid; i < NTOT; i += 256) {
    int c = hist[labels[i & (BSZ - 1)]];
    float M = __uint_as_float(rowM[i]);
    // per_anchor = rowA - M * (N + 1 - 4c)
    float per = rowA[i] - M * (float)(NTOT + 1 - 4 * c);
    acc += (double)per;
  }
#pragma unroll
  for (int d = 1; d < 64; d <<= 1) acc += __shfl_xor(acc, d, 64);
  if ((tid & 63) == 0) wsum[tid >> 6] = acc;
  __syncthreads();
  if (tid == 0) {
    double t = wsum[0] + wsum[1] + wsum[2] + wsum[3];
    out[0] = (float)(-t / (double)NTOT);   // loss = -(T/baseT)*mean(per), T/baseT=1
  }
}

extern "C" void kernel_launch(void* const* d_in, const int* in_sizes, int n_in,
                              void* d_out, int out_size, void* d_ws, size_t ws_size,
                              hipStream_t stream) {
  const float* feat = (const float*)d_in[0];   // [4096, 2, 512] fp32
  const int* labels = (const int*)d_in[1];     // [4096] int
  float* out = (float*)d_out;                  // scalar

  // Workspace layout: bf16 X (8 MB) | rowA fp32 (32 KB) | rowM u32 (32 KB)
  unsigned short* X = (unsigned short*)d_ws;
  float* rowA = (float*)((char*)d_ws + (size_t)NTOT * D * 2);
  unsigned int* rowM = (unsigned int*)((char*)rowA + (size_t)NTOT * 4);

  prep_kernel<<<2048, 256, 0, stream>>>(feat, X, rowA, rowM);
  dim3 grid(NTOT / BN, NTOT / BM);
  gram_kernel<<<grid, 256, 0, stream>>>(X, labels, rowA, rowM);
  finalize_kernel<<<1, 256, 0, stream>>>(labels, rowA, rowM, out);
}

// Round 2
// 200.180 us; speedup vs baseline: 1.0291x; 1.0291x over previous
//
#include <hip/hip_runtime.h>
#include <hip/hip_bf16.h>

// Problem constants (fixed by setup_inputs)
#define BSZ  4096
#define NTOT 8192      // bsz * n_views
#define D    512
#define NCLS 100
#define INV_T 14.285714285714286f   // 1/0.07

typedef __attribute__((ext_vector_type(4))) float f32x4;
typedef __attribute__((ext_vector_type(8))) short bf16x8;

// round-to-nearest-even fp32 -> bf16
__device__ __forceinline__ unsigned short f2bf(float f) {
  union { float f; unsigned int u; } v; v.f = f;
  unsigned int u = v.u;
  u += 0x7fffu + ((u >> 16) & 1u);
  return (unsigned short)(u >> 16);
}

// Kernel 1: build bf16 contrast matrix X[N][D] (view-swap layout), vectorized
// 8 elems/thread; zero row accumulators. contrast[v*BSZ+b][k] = feat[b][v][k].
// Launch with exactly NTOT*D/8 = 524288 threads.
__global__ void prep_kernel(const float* __restrict__ feat,
                            unsigned short* __restrict__ X,
                            float* __restrict__ rowA,
                            unsigned int* __restrict__ rowM) {
  int idx = blockIdx.x * blockDim.x + threadIdx.x;
  int row = idx >> 6;            // 64 chunks of 8 per row of 512
  int kc = (idx & 63) << 3;
  int v = row >> 12;
  int b = row & (BSZ - 1);
  const float* src = feat + ((size_t)(((b << 1) + v)) << 9) + kc;
  f32x4 f0 = *(const f32x4*)src;
  f32x4 f1 = *(const f32x4*)(src + 4);
  bf16x8 ov;
  ov[0] = (short)f2bf(f0[0]); ov[1] = (short)f2bf(f0[1]);
  ov[2] = (short)f2bf(f0[2]); ov[3] = (short)f2bf(f0[3]);
  ov[4] = (short)f2bf(f1[0]); ov[5] = (short)f2bf(f1[1]);
  ov[6] = (short)f2bf(f1[2]); ov[7] = (short)f2bf(f1[3]);
  *(bf16x8*)(X + (size_t)row * D + kc) = ov;
  if (idx < NTOT) { rowA[idx] = 0.f; rowM[idx] = 0u; }
}

// Kernel 2: fused Gram + epilogue. 256x256 tile, BK=64, 8 waves (2x4),
// double-buffered LDS with stage-before-compute (2-phase pipeline).
#define BM 256
#define BN 256
#define BK 64
#define KSTEPS (D / BK)   // 8

__global__ __launch_bounds__(512, 2) void gram_kernel(
    const unsigned short* __restrict__ X,
    const int* __restrict__ labels,
    float* __restrict__ rowA,
    unsigned int* __restrict__ rowM) {
  // 2 bufs x (A 32KB + B 32KB) = 128 KiB
  __shared__ __align__(16) unsigned short sA[2][BM * BK];
  __shared__ __align__(16) unsigned short sB[2][BN * BK];

  const int tid = threadIdx.x;
  const int lane = tid & 63;
  const int wid = tid >> 6;          // 0..7
  const int wr = wid >> 2;           // 0..1 : wave row (128 rows each)
  const int wc = wid & 3;            // 0..3 : wave col (64 cols each)
  const int l15 = lane & 15;
  const int lg = lane >> 4;

  // XCD-aware swizzle: 1024 blocks, 8 XCDs, 128 consecutive per XCD.
  int bid = blockIdx.x;
  int swz = (bid & 7) * 128 + (bid >> 3);
  const int rowBase = (swz >> 5) * BM;   // 32x32 tile grid
  const int colBase = (swz & 31) * BN;

  // Stage one BK-slice of A and B tiles (32 KB each) into buf.
  // global_load_lds: LDS dest is wave-uniform base + lane*16 (linear layout);
  // per-lane global source carries the lane offset.
  auto STAGE = [&](int buf, int k0) {
#pragma unroll
    for (int r = 0; r < 4; ++r) {
      int flat = r * 8192 + wid * 1024 + lane * 16;  // byte offset in 32KB tile
      int row = flat >> 7;                           // 128 B per row (64 bf16)
      int ke = (flat & 127) >> 1;                    // element offset in row
      __builtin_amdgcn_global_load_lds(
          (const __attribute__((address_space(1))) void*)
              (X + (size_t)(rowBase + row) * D + k0 + ke),
          (__attribute__((address_space(3))) void*)
              ((char*)&sA[buf][0] + r * 8192 + wid * 1024),
          16, 0, 0);
      __builtin_amdgcn_global_load_lds(
          (const __attribute__((address_space(1))) void*)
              (X + (size_t)(colBase + row) * D + k0 + ke),
          (__attribute__((address_space(3))) void*)
              ((char*)&sB[buf][0] + r * 8192 + wid * 1024),
          16, 0, 0);
    }
  };

  f32x4 acc[8][4] = {};   // 8x4 fragments of 16x16 per wave (128x64 output)

  STAGE(0, 0);
  __syncthreads();        // drains vmcnt for every wave -> buf0 ready
#pragma unroll
  for (int t = 0; t < KSTEPS; ++t) {
    const int cur = t & 1;
    if (t + 1 < KSTEPS) STAGE(cur ^ 1, (t + 1) * BK);  // prefetch next slice
#pragma unroll
    for (int kk = 0; kk < 2; ++kk) {
      bf16x8 a[8], b[4];
#pragma unroll
      for (int mi = 0; mi < 8; ++mi)
        a[mi] = *(const bf16x8*)
            (&sA[cur][(wr * 128 + mi * 16 + l15) * BK + kk * 32 + lg * 8]);
#pragma unroll
      for (int nj = 0; nj < 4; ++nj)
        b[nj] = *(const bf16x8*)
            (&sB[cur][(wc * 64 + nj * 16 + l15) * BK + kk * 32 + lg * 8]);
#pragma unroll
      for (int mi = 0; mi < 8; ++mi)
#pragma unroll
        for (int nj = 0; nj < 4; ++nj)
          acc[mi][nj] = __builtin_amdgcn_mfma_f32_16x16x32_bf16(
              a[mi], b[nj], acc[mi][nj], 0, 0, 0);
    }
    __syncthreads();      // next buf staged + this buf's readers done
  }

  // Epilogue: C/D mapping (16x16x32): col = lane&15, row = (lane>>4)*4 + reg.
  int colLab[4];
#pragma unroll
  for (int nj = 0; nj < 4; ++nj)
    colLab[nj] = labels[(colBase + wc * 64 + nj * 16 + l15) & (BSZ - 1)];

#pragma unroll
  for (int mi = 0; mi < 8; ++mi) {
#pragma unroll
    for (int reg = 0; reg < 4; ++reg) {
      int rit = wr * 128 + mi * 16 + lg * 4 + reg;
      int i = rowBase + rit;
      int li = labels[i & (BSZ - 1)];
      float s = 0.f, mx = 0.f;
#pragma unroll
      for (int nj = 0; nj < 4; ++nj) {
        int j = colBase + wc * 64 + nj * 16 + l15;
        float g = acc[mi][nj][reg];
        float sim = g * g * INV_T;
        mx = fmaxf(mx, sim);                    // max INCLUDES diagonal
        float sgn = (i == j) ? 0.f : ((li == colLab[nj]) ? -1.f : 1.f);
        s = fmaf(sim, sgn, s);
      }
      // reduce across the 16 lanes holding this row's 16 columns
#pragma unroll
      for (int d = 1; d < 16; d <<= 1) {
        s += __shfl_xor(s, d, 64);
        mx = fmaxf(mx, __shfl_xor(mx, d, 64));
      }
      if (l15 == 0) {
        atomicAdd(&rowA[i], s);
        atomicMax(&rowM[i], __float_as_uint(mx));   // sim >= 0: uint-order ok
      }
    }
  }
}

// Kernel 3: label histogram + final reduction (double accum: fp32 sum of
// 8192 values of ~3e10 magnitude would random-walk ~7e8, at threshold).
__global__ void finalize_kernel(const int* __restrict__ labels,
                                const float* __restrict__ rowA,
                                const unsigned int* __restrict__ rowM,
                                float* __restrict__ out) {
  __shared__ int hist[NCLS];
  __shared__ double wsum[4];
  int tid = threadIdx.x;
  for (int c = tid; c < NCLS; c += 256) hist[c] = 0;
  __syncthreads();
  for (int b = tid; b < BSZ; b += 256) atomicAdd(&hist[labels[b]], 1);
  __syncthreads();
  double acc = 0.0;
  for (int i = tid; i < NTOT; i += 256) {
    int c = hist[labels[i & (BSZ - 1)]];
    float M = __uint_as_float(rowM[i]);
    // per_anchor = rowA - M * (N + 1 - 4c)
    float per = rowA[i] - M * (float)(NTOT + 1 - 4 * c);
    acc += (double)per;
  }
#pragma unroll
  for (int d = 1; d < 64; d <<= 1) acc += __shfl_xor(acc, d, 64);
  if ((tid & 63) == 0) wsum[tid >> 6] = acc;
  __syncthreads();
  if (tid == 0) {
    double t = wsum[0] + wsum[1] + wsum[2] + wsum[3];
    out[0] = (float)(-t / (double)NTOT);   // T/baseT = 1
  }
}

extern "C" void kernel_launch(void* const* d_in, const int* in_sizes, int n_in,
                              void* d_out, int out_size, void* d_ws, size_t ws_size,
                              hipStream_t stream) {
  const float* feat = (const float*)d_in[0];   // [4096, 2, 512] fp32
  const int* labels = (const int*)d_in[1];     // [4096] int
  float* out = (float*)d_out;                  // scalar

  // Workspace: bf16 X (8 MB) | rowA fp32 (32 KB) | rowM u32 (32 KB)
  unsigned short* X = (unsigned short*)d_ws;
  float* rowA = (float*)((char*)d_ws + (size_t)NTOT * D * 2);
  unsigned int* rowM = (unsigned int*)((char*)rowA + (size_t)NTOT * 4);

  prep_kernel<<<2048, 256, 0, stream>>>(feat, X, rowA, rowM);
  gram_kernel<<<1024, 512, 0, stream>>>(X, labels, rowA, rowM);
  finalize_kernel<<<1, 256, 0, stream>>>(labels, rowA, rowM, out);
}

// Round 3
// 184.642 us; speedup vs baseline: 1.1157x; 1.0841x over previous
//
#include <hip/hip_runtime.h>
#include <hip/hip_bf16.h>

// Problem constants (fixed by setup_inputs)
#define BSZ  4096
#define NTOT 8192      // bsz * n_views
#define D    512
#define NCLS 100
#define INV_T 14.285714285714286f   // 1/0.07

typedef __attribute__((ext_vector_type(4))) float f32x4;
typedef __attribute__((ext_vector_type(8))) short bf16x8;

// round-to-nearest-even fp32 -> bf16
__device__ __forceinline__ unsigned short f2bf(float f) {
  union { float f; unsigned int u; } v; v.f = f;
  unsigned int u = v.u;
  u += 0x7fffu + ((u >> 16) & 1u);
  return (unsigned short)(u >> 16);
}

// Kernel 1: build bf16 contrast matrix X[N][D] (view-swap layout), vectorized
// 8 elems/thread; zero row accumulators. contrast[v*BSZ+b][k] = feat[b][v][k].
// Launch with exactly NTOT*D/8 = 524288 threads.
__global__ void prep_kernel(const float* __restrict__ feat,
                            unsigned short* __restrict__ X,
                            float* __restrict__ rowA,
                            unsigned int* __restrict__ rowM) {
  int idx = blockIdx.x * blockDim.x + threadIdx.x;
  int row = idx >> 6;            // 64 chunks of 8 per row of 512
  int kc = (idx & 63) << 3;
  int v = row >> 12;
  int b = row & (BSZ - 1);
  const float* src = feat + ((size_t)(((b << 1) + v)) << 9) + kc;
  f32x4 f0 = *(const f32x4*)src;
  f32x4 f1 = *(const f32x4*)(src + 4);
  bf16x8 ov;
  ov[0] = (short)f2bf(f0[0]); ov[1] = (short)f2bf(f0[1]);
  ov[2] = (short)f2bf(f0[2]); ov[3] = (short)f2bf(f0[3]);
  ov[4] = (short)f2bf(f1[0]); ov[5] = (short)f2bf(f1[1]);
  ov[6] = (short)f2bf(f1[2]); ov[7] = (short)f2bf(f1[3]);
  *(bf16x8*)(X + (size_t)row * D + kc) = ov;
  if (idx < NTOT) { rowA[idx] = 0.f; rowM[idx] = 0u; }
}

// Kernel 2: fused Gram + epilogue. 256x256 tile, BK=32, 8 waves (2x4).
// 3-buffer LDS pipeline, distance-2 prefetch, counted vmcnt (never 0 in
// steady state), ONE raw s_barrier per K-tile, T2 XOR swizzle, T5 setprio.
#define BM 256
#define BN 256
#define BK 32
#define NT (D / BK)   // 16 K-tiles

__global__ __launch_bounds__(512, 2) void gram_kernel(
    const unsigned short* __restrict__ X,
    const int* __restrict__ labels,
    float* __restrict__ rowA,
    unsigned int* __restrict__ rowM) {
  // 3 bufs x 16 KB each for A and B = 96 KiB total.
  // Layout per buf: [256 rows][32 cols] bf16 (64 B rows), halves contiguous.
  __shared__ __align__(16) unsigned short sA[3][BM * BK];
  __shared__ __align__(16) unsigned short sB[3][BN * BK];

  const int tid = threadIdx.x;
  const int lane = tid & 63;
  const int wid = tid >> 6;          // 0..7
  const int wr = wid >> 2;           // 0..1 : wave row (128 rows each)
  const int wc = wid & 3;            // 0..3 : wave col (64 cols each)
  const int l15 = lane & 15;
  const int lg = lane >> 4;

  // XCD-aware swizzle: 1024 blocks, 8 XCDs, 128 consecutive per XCD.
  const int bid = blockIdx.x;
  const int swz = (bid & 7) * 128 + (bid >> 3);
  const int rowBase = (swz >> 5) * BM;   // 32x32 tile grid
  const int colBase = (swz & 31) * BN;

  // T2 swizzle: logical granule16 c16 of row stored at physical
  // p = c16 ^ ((row ^ (row>>2)) & 3). For frag reads row==l15 (mod 16) so the
  // physical column byte-offset is a per-thread CONSTANT:
  const int sR = (l15 ^ (l15 >> 2)) & 3;
  const int rdOff = ((lg ^ sR) & 3) * 16;        // byte offset within 64B row
  // Stage side (rule #21): linear LDS dest (lane*16), inverse-swizzled source.
  const int stRow = tid >> 2;                    // local row this thread fills
  const int srcC16 = (tid & 3) ^ ((stRow ^ (stRow >> 2)) & 3);

  // Stage one half-tile (128 rows x 32 cols = 8 KB): 1 gload_lds per wave.
  auto stage_half = [&](unsigned short* dstBase, int srcRow0, int k0) {
    __builtin_amdgcn_global_load_lds(
        (const __attribute__((address_space(1))) void*)
            (X + (size_t)(srcRow0 + stRow) * D + k0 + srcC16 * 8),
        (__attribute__((address_space(3))) void*)
            ((char*)dstBase + wid * 1024),
        16, 0, 0);
  };
  // Stage a full K-tile (A0, A1, B0, B1): 4 gload_lds per wave.
  auto stage_tile = [&](int buf, int k0) {
    stage_half(&sA[buf][0],        rowBase,       k0);
    stage_half(&sA[buf][128 * BK], rowBase + 128, k0);
    stage_half(&sB[buf][0],        colBase,       k0);
    stage_half(&sB[buf][128 * BK], colBase + 128, k0);
  };

  f32x4 acc[8][4] = {};   // 8x4 fragments of 16x16 per wave (128x64 output)

  // Prologue: stage tiles 0 and 1 (8 loads/wave in flight).
  stage_tile(0, 0);
  stage_tile(1, BK);

#pragma unroll
  for (int t = 0; t < NT; ++t) {
    // Gate: tile t's 4 loads (older than the newest 4 = tile t+1's) complete;
    // lgkmcnt(0) drains this wave's LDS reads of buf (t+2)%3's previous tenant.
    if (t == NT - 1)
      asm volatile("s_waitcnt vmcnt(0) lgkmcnt(0)" ::: "memory");
    else
      asm volatile("s_waitcnt vmcnt(4) lgkmcnt(0)" ::: "memory");
    __builtin_amdgcn_s_barrier();       // raw barrier: no vmcnt(0) drain
    __builtin_amdgcn_sched_barrier(0);

    // Distance-2 prefetch into the buffer nobody reads this tile.
    if (t + 2 < NT) stage_tile((t + 2) % 3, (t + 2) * BK);

    // Compute tile t from buf t%3.
    const unsigned short* A = &sA[t % 3][0];
    const unsigned short* B = &sB[t % 3][0];
    bf16x8 a[8], b[4];
#pragma unroll
    for (int mi = 0; mi < 8; ++mi)
      a[mi] = *(const bf16x8*)
          ((const char*)A + (wr * 128 + mi * 16 + l15) * 64 + rdOff);
#pragma unroll
    for (int nj = 0; nj < 4; ++nj)
      b[nj] = *(const bf16x8*)
          ((const char*)B + (wc * 64 + nj * 16 + l15) * 64 + rdOff);

    __builtin_amdgcn_s_setprio(1);
#pragma unroll
    for (int mi = 0; mi < 8; ++mi)
#pragma unroll
      for (int nj = 0; nj < 4; ++nj)
        acc[mi][nj] = __builtin_amdgcn_mfma_f32_16x16x32_bf16(
            a[mi], b[nj], acc[mi][nj], 0, 0, 0);
    __builtin_amdgcn_s_setprio(0);
  }

  // Epilogue: C/D mapping (16x16x32): col = lane&15, row = (lane>>4)*4 + reg.
  int colLab[4];
#pragma unroll
  for (int nj = 0; nj < 4; ++nj)
    colLab[nj] = labels[(colBase + wc * 64 + nj * 16 + l15) & (BSZ - 1)];

#pragma unroll
  for (int mi = 0; mi < 8; ++mi) {
#pragma unroll
    for (int reg = 0; reg < 4; ++reg) {
      int rit = wr * 128 + mi * 16 + lg * 4 + reg;
      int i = rowBase + rit;
      int li = labels[i & (BSZ - 1)];
      float s = 0.f, mx = 0.f;
#pragma unroll
      for (int nj = 0; nj < 4; ++nj) {
        int j = colBase + wc * 64 + nj * 16 + l15;
        float g = acc[mi][nj][reg];
        float sim = g * g * INV_T;
        mx = fmaxf(mx, sim);                    // max INCLUDES diagonal
        float sgn = (i == j) ? 0.f : ((li == colLab[nj]) ? -1.f : 1.f);
        s = fmaf(sim, sgn, s);
      }
      // reduce across the 16 lanes holding this row's 16 columns
#pragma unroll
      for (int d = 1; d < 16; d <<= 1) {
        s += __shfl_xor(s, d, 64);
        mx = fmaxf(mx, __shfl_xor(mx, d, 64));
      }
      if (l15 == 0) {
        atomicAdd(&rowA[i], s);
        atomicMax(&rowM[i], __float_as_uint(mx));   // sim >= 0: uint-order ok
      }
    }
  }
}

// Kernel 3: label histogram + final reduction (double accum: fp32 sum of
// 8192 values of ~3e10 magnitude would random-walk ~7e8, at threshold).
__global__ void finalize_kernel(const int* __restrict__ labels,
                                const float* __restrict__ rowA,
                                const unsigned int* __restrict__ rowM,
                                float* __restrict__ out) {
  __shared__ int hist[NCLS];
  __shared__ double wsum[4];
  int tid = threadIdx.x;
  for (int c = tid; c < NCLS; c += 256) hist[c] = 0;
  __syncthreads();
  for (int b = tid; b < BSZ; b += 256) atomicAdd(&hist[labels[b]], 1);
  __syncthreads();
  double acc = 0.0;
  for (int i = tid; i < NTOT; i += 256) {
    int c = hist[labels[i & (BSZ - 1)]];
    float M = __uint_as_float(rowM[i]);
    // per_anchor = rowA - M * (N + 1 - 4c)
    float per = rowA[i] - M * (float)(NTOT + 1 - 4 * c);
    acc += (double)per;
  }
#pragma unroll
  for (int d = 1; d < 64; d <<= 1) acc += __shfl_xor(acc, d, 64);
  if ((tid & 63) == 0) wsum[tid >> 6] = acc;
  __syncthreads();
  if (tid == 0) {
    double t = wsum[0] + wsum[1] + wsum[2] + wsum[3];
    out[0] = (float)(-t / (double)NTOT);   // T/baseT = 1
  }
}

extern "C" void kernel_launch(void* const* d_in, const int* in_sizes, int n_in,
                              void* d_out, int out_size, void* d_ws, size_t ws_size,
                              hipStream_t stream) {
  const float* feat = (const float*)d_in[0];   // [4096, 2, 512] fp32
  const int* labels = (const int*)d_in[1];     // [4096] int
  float* out = (float*)d_out;                  // scalar

  // Workspace: bf16 X (8 MB) | rowA fp32 (32 KB) | rowM u32 (32 KB)
  unsigned short* X = (unsigned short*)d_ws;
  float* rowA = (float*)((char*)d_ws + (size_t)NTOT * D * 2);
  unsigned int* rowM = (unsigned int*)((char*)rowA + (size_t)NTOT * 4);

  prep_kernel<<<2048, 256, 0, stream>>>(feat, X, rowA, rowM);
  gram_kernel<<<1024, 512, 0, stream>>>(X, labels, rowA, rowM);
  finalize_kernel<<<1, 256, 0, stream>>>(labels, rowA, rowM, out);
}

// Round 4
// 142.252 us; speedup vs baseline: 1.4482x; 1.2980x over previous
//
#include <hip/hip_runtime.h>
#include <hip/hip_bf16.h>
#include <math.h>

// Problem constants (fixed by setup_inputs)
#define BSZ  4096
#define NTOT 8192      // bsz * n_views
#define D    512
#define NCLS 100
#define INV_T 14.285714285714286f   // 1/0.07

typedef __attribute__((ext_vector_type(4))) float f32x4;
typedef __attribute__((ext_vector_type(8))) short bf16x8;

// round-to-nearest-even fp32 -> bf16
__device__ __forceinline__ unsigned short f2bf(float f) {
  union { float f; unsigned int u; } v; v.f = f;
  unsigned int u = v.u;
  u += 0x7fffu + ((u >> 16) & 1u);
  return (unsigned short)(u >> 16);
}

// Kernel 1: build bf16 contrast matrix X[N][D] (view-swap layout), vectorized
// 8 elems/thread; zero row accumulators. contrast[v*BSZ+b][k] = feat[b][v][k].
// Launch with exactly NTOT*D/8 = 524288 threads.
__global__ void prep_kernel(const float* __restrict__ feat,
                            unsigned short* __restrict__ X,
                            float* __restrict__ rowA,
                            unsigned int* __restrict__ rowM) {
  int idx = blockIdx.x * blockDim.x + threadIdx.x;
  int row = idx >> 6;            // 64 chunks of 8 per row of 512
  int kc = (idx & 63) << 3;
  int v = row >> 12;
  int b = row & (BSZ - 1);
  const float* src = feat + ((size_t)(((b << 1) + v)) << 9) + kc;
  f32x4 f0 = *(const f32x4*)src;
  f32x4 f1 = *(const f32x4*)(src + 4);
  bf16x8 ov;
  ov[0] = (short)f2bf(f0[0]); ov[1] = (short)f2bf(f0[1]);
  ov[2] = (short)f2bf(f0[2]); ov[3] = (short)f2bf(f0[3]);
  ov[4] = (short)f2bf(f1[0]); ov[5] = (short)f2bf(f1[1]);
  ov[6] = (short)f2bf(f1[2]); ov[7] = (short)f2bf(f1[3]);
  *(bf16x8*)(X + (size_t)row * D + kc) = ov;
  if (idx < NTOT) { rowA[idx] = 0.f; rowM[idx] = 0u; }
}

// Kernel 2: fused Gram + epilogue, TRIANGULAR grid (G and sign mask are
// symmetric). 256x256 tile, BK=32, 8 waves (2x4), 3-buffer LDS with
// distance-2 prefetch, 4 fine phases per K-tile:
//   {1 gload_lds || 2-6 ds_read || barrier || setprio+8 MFMA || barrier}
// counted vmcnt (never 0 until the last tile), T2 XOR swizzle.
#define BM 256
#define BN 256
#define BK 32
#define NT (D / BK)   // 16 K-tiles

__global__ __launch_bounds__(512, 2) void gram_kernel(
    const unsigned short* __restrict__ X,
    const int* __restrict__ labels,
    float* __restrict__ rowA,
    unsigned int* __restrict__ rowM) {
  // 3 bufs x 16 KB for A and B = 96 KiB. [256 rows][32 cols] bf16, 64 B rows.
  __shared__ __align__(16) unsigned short sA[3][BM * BK];
  __shared__ __align__(16) unsigned short sB[3][BN * BK];

  const int tid = threadIdx.x;
  const int lane = tid & 63;
  const int wid = tid >> 6;          // 0..7
  const int wr = wid >> 2;           // 0..1 : wave row (128 rows each)
  const int wc = wid & 3;            // 0..3 : wave col (64 cols each)
  const int l15 = lane & 15;
  const int lg = lane >> 4;

  // Triangular tile decode with bijective XCD chunking (528 = 8 * 66).
  const int bid = blockIdx.x;
  const int swz = (bid & 7) * 66 + (bid >> 3);
  int p = (int)((sqrtf(8.f * (float)swz + 1.f) - 1.f) * 0.5f);
  while ((p + 1) * (p + 2) / 2 <= swz) ++p;
  while (p * (p + 1) / 2 > swz) --p;
  const int q = swz - p * (p + 1) / 2;      // 0 <= q <= p <= 31
  const int rowBase = p << 8;
  const int colBase = q << 8;
  const bool diag = (p == q);

  // T2 swizzle: granule16 c16 of row stored at p16 = c16 ^ ((row^(row>>2))&3).
  // Fragment reads have row === l15 (mod 16) -> per-thread constant offset.
  const int sR = (l15 ^ (l15 >> 2)) & 3;
  const int rdOff = ((lg ^ sR) & 3) * 16;        // byte offset within 64B row
  // Stage side: linear LDS dest (lane*16), inverse-swizzled global source.
  const int stRow = tid >> 2;                    // local row this thread fills
  const int srcC16 = (tid & 3) ^ ((stRow ^ (stRow >> 2)) & 3);

  // Stage one half-tile (128 rows x 32 cols = 8 KB): 1 gload_lds per wave.
  auto stage_half = [&](unsigned short* dstBase, int srcRow0, int k0) {
    __builtin_amdgcn_global_load_lds(
        (const __attribute__((address_space(1))) void*)
            (X + (size_t)(srcRow0 + stRow) * D + k0 + srcC16 * 8),
        (__attribute__((address_space(3))) void*)
            ((char*)dstBase + wid * 1024),
        16, 0, 0);
  };

  f32x4 acc[8][4] = {};   // 8x4 fragments of 16x16 per wave (128x64 output)

  // Prologue: stage tiles 0 and 1 (8 loads/wave), gate tile 0 (vmcnt(4)).
#pragma unroll
  for (int t0 = 0; t0 < 2; ++t0) {
    stage_half(&sA[t0][0],        rowBase,       t0 * BK);
    stage_half(&sA[t0][128 * BK], rowBase + 128, t0 * BK);
    stage_half(&sB[t0][0],        colBase,       t0 * BK);
    stage_half(&sB[t0][128 * BK], colBase + 128, t0 * BK);
  }
  asm volatile("s_waitcnt vmcnt(4)" ::: "memory");
  __builtin_amdgcn_s_barrier();

#pragma unroll
  for (int t = 0; t < NT; ++t) {
    const unsigned short* A = &sA[t % 3][0];
    const unsigned short* B = &sB[t % 3][0];
    const int bufN = (t + 2) % 3;
    bf16x8 b[4];
#pragma unroll
    for (int ph = 0; ph < 4; ++ph) {
      // Stage one half of tile t+2 into buf nobody reads for 2 tiles.
      if (t + 2 < NT) {
        const int k2 = (t + 2) * BK;
        if (ph == 0) stage_half(&sA[bufN][0],        rowBase,       k2);
        if (ph == 1) stage_half(&sA[bufN][128 * BK], rowBase + 128, k2);
        if (ph == 2) stage_half(&sB[bufN][0],        colBase,       k2);
        if (ph == 3) stage_half(&sB[bufN][128 * BK], colBase + 128, k2);
      }
      if (ph == 0) {
#pragma unroll
        for (int nj = 0; nj < 4; ++nj)
          b[nj] = *(const bf16x8*)
              ((const char*)B + (wc * 64 + nj * 16 + l15) * 64 + rdOff);
      }
      bf16x8 a0 = *(const bf16x8*)
          ((const char*)A + (wr * 128 + (2 * ph + 0) * 16 + l15) * 64 + rdOff);
      bf16x8 a1 = *(const bf16x8*)
          ((const char*)A + (wr * 128 + (2 * ph + 1) * 16 + l15) * 64 + rdOff);

      __builtin_amdgcn_s_barrier();      // role-split: all waves enter MFMA
      __builtin_amdgcn_s_setprio(1);
#pragma unroll
      for (int nj = 0; nj < 4; ++nj) {
        acc[2 * ph + 0][nj] = __builtin_amdgcn_mfma_f32_16x16x32_bf16(
            a0, b[nj], acc[2 * ph + 0][nj], 0, 0, 0);
        acc[2 * ph + 1][nj] = __builtin_amdgcn_mfma_f32_16x16x32_bf16(
            a1, b[nj], acc[2 * ph + 1][nj], 0, 0, 0);
      }
      __builtin_amdgcn_s_setprio(0);
      // Fold next tile's vmcnt gate into the last phase barrier.
      if (ph == 3 && t < NT - 1) {
        if (t == NT - 2) asm volatile("s_waitcnt vmcnt(0)" ::: "memory");
        else             asm volatile("s_waitcnt vmcnt(4)" ::: "memory");
      }
      __builtin_amdgcn_s_barrier();      // phase end
    }
  }

  // Epilogue. C/D mapping (16x16x32): col = lane&15, row = (lane>>4)*4 + reg.
  // Off-diagonal blocks credit BOTH row i (row-side) and row j (col-side);
  // sim and sign are symmetric. Diagonal blocks: row-side only (full square
  // computed, every unordered pair appears twice in-block), zero at i==j.
  int colLab[4];
#pragma unroll
  for (int nj = 0; nj < 4; ++nj)
    colLab[nj] = labels[(colBase + wc * 64 + nj * 16 + l15) & (BSZ - 1)];

  float cs[4] = {0.f, 0.f, 0.f, 0.f};
  float cm[4] = {0.f, 0.f, 0.f, 0.f};

#pragma unroll
  for (int mi = 0; mi < 8; ++mi) {
#pragma unroll
    for (int reg = 0; reg < 4; ++reg) {
      int rit = wr * 128 + mi * 16 + lg * 4 + reg;
      int i = rowBase + rit;
      int li = labels[i & (BSZ - 1)];
      float s = 0.f, mx = 0.f;
#pragma unroll
      for (int nj = 0; nj < 4; ++nj) {
        int j = colBase + wc * 64 + nj * 16 + l15;
        float g = acc[mi][nj][reg];
        float sim = g * g * INV_T;
        float sgn = (li == colLab[nj]) ? -1.f : 1.f;
        if (diag && i == j) sgn = 0.f;
        mx = fmaxf(mx, sim);                    // max INCLUDES diagonal
        s = fmaf(sim, sgn, s);
        if (!diag) {
          cs[nj] = fmaf(sim, sgn, cs[nj]);      // column j gets same credit
          cm[nj] = fmaxf(cm[nj], sim);
        }
      }
      // row-side: reduce over the 16 lanes holding this row's 16 columns
#pragma unroll
      for (int d = 1; d < 16; d <<= 1) {
        s += __shfl_xor(s, d, 64);
        mx = fmaxf(mx, __shfl_xor(mx, d, 64));
      }
      if (l15 == 0) {
        atomicAdd(&rowA[i], s);
        atomicMax(&rowM[i], __float_as_uint(mx));   // sim >= 0: uint-order ok
      }
    }
  }
  if (!diag) {
    // col-side: rows were summed in-thread (mi,reg); finish across lg groups.
#pragma unroll
    for (int nj = 0; nj < 4; ++nj) {
      float s = cs[nj], mx = cm[nj];
      s += __shfl_xor(s, 16, 64);
      mx = fmaxf(mx, __shfl_xor(mx, 16, 64));
      s += __shfl_xor(s, 32, 64);
      mx = fmaxf(mx, __shfl_xor(mx, 32, 64));
      if (lg == 0) {
        int j = colBase + wc * 64 + nj * 16 + l15;
        atomicAdd(&rowA[j], s);
        atomicMax(&rowM[j], __float_as_uint(mx));
      }
    }
  }
}

// Kernel 3: label histogram + final reduction (double accum: fp32 sum of
// 8192 values of ~3e10 magnitude would random-walk ~7e8, at threshold).
__global__ void finalize_kernel(const int* __restrict__ labels,
                                const float* __restrict__ rowA,
                                const unsigned int* __restrict__ rowM,
                                float* __restrict__ out) {
  __shared__ int hist[NCLS];
  __shared__ double wsum[4];
  int tid = threadIdx.x;
  for (int c = tid; c < NCLS; c += 256) hist[c] = 0;
  __syncthreads();
  for (int b = tid; b < BSZ; b += 256) atomicAdd(&hist[labels[b]], 1);
  __syncthreads();
  double acc = 0.0;
  for (int i = tid; i < NTOT; i += 256) {
    int c = hist[labels[i & (BSZ - 1)]];
    float M = __uint_as_float(rowM[i]);
    // per_anchor = rowA - M * (N + 1 - 4c)
    float per = rowA[i] - M * (float)(NTOT + 1 - 4 * c);
    acc += (double)per;
  }
#pragma unroll
  for (int d = 1; d < 64; d <<= 1) acc += __shfl_xor(acc, d, 64);
  if ((tid & 63) == 0) wsum[tid >> 6] = acc;
  __syncthreads();
  if (tid == 0) {
    double t = wsum[0] + wsum[1] + wsum[2] + wsum[3];
    out[0] = (float)(-t / (double)NTOT);   // T/baseT = 1
  }
}

extern "C" void kernel_launch(void* const* d_in, const int* in_sizes, int n_in,
                              void* d_out, int out_size, void* d_ws, size_t ws_size,
                              hipStream_t stream) {
  const float* feat = (const float*)d_in[0];   // [4096, 2, 512] fp32
  const int* labels = (const int*)d_in[1];     // [4096] int
  float* out = (float*)d_out;                  // scalar

  // Workspace: bf16 X (8 MB) | rowA fp32 (32 KB) | rowM u32 (32 KB)
  unsigned short* X = (unsigned short*)d_ws;
  float* rowA = (float*)((char*)d_ws + (size_t)NTOT * D * 2);
  unsigned int* rowM = (unsigned int*)((char*)rowA + (size_t)NTOT * 4);

  prep_kernel<<<2048, 256, 0, stream>>>(feat, X, rowA, rowM);
  gram_kernel<<<528, 512, 0, stream>>>(X, labels, rowA, rowM);
  finalize_kernel<<<1, 256, 0, stream>>>(labels, rowA, rowM, out);
}

// Round 5
// 130.901 us; speedup vs baseline: 1.5738x; 1.0867x over previous
//
#include <hip/hip_runtime.h>
#include <hip/hip_bf16.h>
#include <math.h>

// Problem constants (fixed by setup_inputs)
#define BSZ  4096
#define NTOT 8192      // bsz * n_views
#define D    512
#define NCLS 100
#define INV_T 14.285714285714286f   // 1/0.07

typedef __attribute__((ext_vector_type(4))) float f32x4;
typedef __attribute__((ext_vector_type(8))) short bf16x8;

// round-to-nearest-even fp32 -> bf16
__device__ __forceinline__ unsigned short f2bf(float f) {
  union { float f; unsigned int u; } v; v.f = f;
  unsigned int u = v.u;
  u += 0x7fffu + ((u >> 16) & 1u);
  return (unsigned short)(u >> 16);
}

// Kernel 1: build bf16 contrast matrix X[N][D] (view-swap layout), vectorized
// 8 elems/thread; zero row accumulators. contrast[v*BSZ+b][k] = feat[b][v][k].
// Launch with exactly NTOT*D/8 = 524288 threads.
__global__ void prep_kernel(const float* __restrict__ feat,
                            unsigned short* __restrict__ X,
                            float* __restrict__ rowA,
                            unsigned int* __restrict__ rowM) {
  int idx = blockIdx.x * blockDim.x + threadIdx.x;
  int row = idx >> 6;            // 64 chunks of 8 per row of 512
  int kc = (idx & 63) << 3;
  int v = row >> 12;
  int b = row & (BSZ - 1);
  const float* src = feat + ((size_t)(((b << 1) + v)) << 9) + kc;
  f32x4 f0 = *(const f32x4*)src;
  f32x4 f1 = *(const f32x4*)(src + 4);
  bf16x8 ov;
  ov[0] = (short)f2bf(f0[0]); ov[1] = (short)f2bf(f0[1]);
  ov[2] = (short)f2bf(f0[2]); ov[3] = (short)f2bf(f0[3]);
  ov[4] = (short)f2bf(f1[0]); ov[5] = (short)f2bf(f1[1]);
  ov[6] = (short)f2bf(f1[2]); ov[7] = (short)f2bf(f1[3]);
  *(bf16x8*)(X + (size_t)row * D + kc) = ov;
  if (idx < NTOT) { rowA[idx] = 0.f; rowM[idx] = 0u; }
}

// Kernel 2: fused Gram + epilogue, TRIANGULAR grid. m97-class geometry:
// 128x128 tile, 4 waves (2x2, each 64x64 -> 64 AGPR acc), BK=32,
// double-buffered 32 KiB LDS, 2-phase template (stage-next-before-compute,
// ONE __syncthreads per K-tile; vmcnt drain hidden by multi-block TLP).
#define BM 128
#define BK 32
#define NT (D / BK)       // 16 K-tiles
#define NRT (NTOT / BM)   // 64 row-tiles
#define NBLK (NRT * (NRT + 1) / 2)   // 2080 triangular blocks

__global__ __launch_bounds__(256, 3) void gram_kernel(
    const unsigned short* __restrict__ X,
    const int* __restrict__ labels,
    float* __restrict__ rowA,
    unsigned int* __restrict__ rowM) {
  // 2 bufs x (A 8KB + B 8KB) = 32 KiB. [128 rows][32 cols] bf16, 64 B rows.
  __shared__ __align__(16) unsigned short sA[2][BM * BK];
  __shared__ __align__(16) unsigned short sB[2][BM * BK];

  const int tid = threadIdx.x;
  const int lane = tid & 63;
  const int wid = tid >> 6;          // 0..3
  const int wr = wid >> 1;           // 0..1 : wave row (64 rows each)
  const int wc = wid & 1;            // 0..1 : wave col (64 cols each)
  const int l15 = lane & 15;
  const int lg = lane >> 4;

  // Triangular tile decode, bijective XCD chunking (2080 = 8 * 260).
  const int bid = blockIdx.x;
  const int swz = (bid & 7) * (NBLK / 8) + (bid >> 3);
  int p = (int)((sqrtf(8.f * (float)swz + 1.f) - 1.f) * 0.5f);
  while ((p + 1) * (p + 2) / 2 <= swz) ++p;
  while (p * (p + 1) / 2 > swz) --p;
  const int q = swz - p * (p + 1) / 2;      // 0 <= q <= p < 64
  const int rowBase = p * BM;
  const int colBase = q * BM;
  const bool diag = (p == q);

  // T2 swizzle: granule16 c16 of row stored at p16 = c16 ^ ((row^(row>>2))&3).
  // Fragment reads have row === l15 (mod 16) -> per-thread constant offset.
  const int sR = (l15 ^ (l15 >> 2)) & 3;
  const int rdOff = ((lg ^ sR) & 3) * 16;        // byte offset within 64B row
  // Stage side: linear LDS dest (lane*16), inverse-swizzled global source.
  // 256 threads x 16B = 4 KB per round; 2 rounds per 8 KB tile.
  int stRow[2], stC16[2];
#pragma unroll
  for (int r = 0; r < 2; ++r) {
    int flat = r * 4096 + tid * 16;
    stRow[r] = flat >> 6;
    stC16[r] = ((flat >> 4) & 3) ^ ((stRow[r] ^ (stRow[r] >> 2)) & 3);
  }

  auto stage_tile = [&](int buf, int k0) {
#pragma unroll
    for (int r = 0; r < 2; ++r) {
      __builtin_amdgcn_global_load_lds(
          (const __attribute__((address_space(1))) void*)
              (X + (size_t)(rowBase + stRow[r]) * D + k0 + stC16[r] * 8),
          (__attribute__((address_space(3))) void*)
              ((char*)&sA[buf][0] + r * 4096 + wid * 1024),
          16, 0, 0);
      __builtin_amdgcn_global_load_lds(
          (const __attribute__((address_space(1))) void*)
              (X + (size_t)(colBase + stRow[r]) * D + k0 + stC16[r] * 8),
          (__attribute__((address_space(3))) void*)
              ((char*)&sB[buf][0] + r * 4096 + wid * 1024),
          16, 0, 0);
    }
  };

  f32x4 acc[4][4] = {};   // 4x4 fragments of 16x16 per wave (64x64 output)

  stage_tile(0, 0);
  __syncthreads();
#pragma unroll
  for (int t = 0; t < NT; ++t) {
    if (t + 1 < NT) stage_tile((t + 1) & 1, (t + 1) * BK);
    const unsigned short* A = &sA[t & 1][0];
    const unsigned short* B = &sB[t & 1][0];
    bf16x8 a[4], b[4];
#pragma unroll
    for (int mi = 0; mi < 4; ++mi)
      a[mi] = *(const bf16x8*)
          ((const char*)A + (wr * 64 + mi * 16 + l15) * 64 + rdOff);
#pragma unroll
    for (int nj = 0; nj < 4; ++nj)
      b[nj] = *(const bf16x8*)
          ((const char*)B + (wc * 64 + nj * 16 + l15) * 64 + rdOff);
#pragma unroll
    for (int mi = 0; mi < 4; ++mi)
#pragma unroll
      for (int nj = 0; nj < 4; ++nj)
        acc[mi][nj] = __builtin_amdgcn_mfma_f32_16x16x32_bf16(
            a[mi], b[nj], acc[mi][nj], 0, 0, 0);
    if (t + 1 < NT) __syncthreads();   // drains vmcnt; hidden by other blocks
  }

  // Epilogue. C/D mapping (16x16x32): col = lane&15, row = (lane>>4)*4 + reg.
  // Off-diagonal blocks credit BOTH row i (row-side) and row j (col-side);
  // sim and sign are symmetric. Diagonal blocks: row-side only (full square
  // computed in-block, every unordered pair appears twice), zero at i==j.
  int colLab[4];
#pragma unroll
  for (int nj = 0; nj < 4; ++nj)
    colLab[nj] = labels[(colBase + wc * 64 + nj * 16 + l15) & (BSZ - 1)];

  float cs[4] = {0.f, 0.f, 0.f, 0.f};
  float cm[4] = {0.f, 0.f, 0.f, 0.f};

#pragma unroll
  for (int mi = 0; mi < 4; ++mi) {
#pragma unroll
    for (int reg = 0; reg < 4; ++reg) {
      int rit = wr * 64 + mi * 16 + lg * 4 + reg;
      int i = rowBase + rit;
      int li = labels[i & (BSZ - 1)];
      float s = 0.f, mx = 0.f;
#pragma unroll
      for (int nj = 0; nj < 4; ++nj) {
        int j = colBase + wc * 64 + nj * 16 + l15;
        float g = acc[mi][nj][reg];
        float sim = g * g * INV_T;
        float sgn = (li == colLab[nj]) ? -1.f : 1.f;
        if (diag && i == j) sgn = 0.f;
        mx = fmaxf(mx, sim);                    // max INCLUDES diagonal
        s = fmaf(sim, sgn, s);
        if (!diag) {
          cs[nj] = fmaf(sim, sgn, cs[nj]);      // column j gets same credit
          cm[nj] = fmaxf(cm[nj], sim);
        }
      }
      // row-side: reduce over the 16 lanes holding this row's 16 columns
#pragma unroll
      for (int d = 1; d < 16; d <<= 1) {
        s += __shfl_xor(s, d, 64);
        mx = fmaxf(mx, __shfl_xor(mx, d, 64));
      }
      if (l15 == 0) {
        atomicAdd(&rowA[i], s);
        atomicMax(&rowM[i], __float_as_uint(mx));   // sim >= 0: uint-order ok
      }
    }
  }
  if (!diag) {
    // col-side: rows were summed in-thread (mi,reg); finish across lg groups.
#pragma unroll
    for (int nj = 0; nj < 4; ++nj) {
      float s = cs[nj], mx = cm[nj];
      s += __shfl_xor(s, 16, 64);
      mx = fmaxf(mx, __shfl_xor(mx, 16, 64));
      s += __shfl_xor(s, 32, 64);
      mx = fmaxf(mx, __shfl_xor(mx, 32, 64));
      if (lg == 0) {
        int j = colBase + wc * 64 + nj * 16 + l15;
        atomicAdd(&rowA[j], s);
        atomicMax(&rowM[j], __float_as_uint(mx));
      }
    }
  }
}

// Kernel 3: label histogram + final reduction (double accum: fp32 sum of
// 8192 values of ~3e10 magnitude would random-walk ~7e8, at threshold).
__global__ void finalize_kernel(const int* __restrict__ labels,
                                const float* __restrict__ rowA,
                                const unsigned int* __restrict__ rowM,
                                float* __restrict__ out) {
  __shared__ int hist[NCLS];
  __shared__ double wsum[4];
  int tid = threadIdx.x;
  for (int c = tid; c < NCLS; c += 256) hist[c] = 0;
  __syncthreads();
  for (int b = tid; b < BSZ; b += 256) atomicAdd(&hist[labels[b]], 1);
  __syncthreads();
  double acc = 0.0;
  for (int i = tid; i < NTOT; i += 256) {
    int c = hist[labels[i & (BSZ - 1)]];
    float M = __uint_as_float(rowM[i]);
    // per_anchor = rowA - M * (N + 1 - 4c)
    float per = rowA[i] - M * (float)(NTOT + 1 - 4 * c);
    acc += (double)per;
  }
#pragma unroll
  for (int d = 1; d < 64; d <<= 1) acc += __shfl_xor(acc, d, 64);
  if ((tid & 63) == 0) wsum[tid >> 6] = acc;
  __syncthreads();
  if (tid == 0) {
    double t = wsum[0] + wsum[1] + wsum[2] + wsum[3];
    out[0] = (float)(-t / (double)NTOT);   // T/baseT = 1
  }
}

extern "C" void kernel_launch(void* const* d_in, const int* in_sizes, int n_in,
                              void* d_out, int out_size, void* d_ws, size_t ws_size,
                              hipStream_t stream) {
  const float* feat = (const float*)d_in[0];   // [4096, 2, 512] fp32
  const int* labels = (const int*)d_in[1];     // [4096] int
  float* out = (float*)d_out;                  // scalar

  // Workspace: bf16 X (8 MB) | rowA fp32 (32 KB) | rowM u32 (32 KB)
  unsigned short* X = (unsigned short*)d_ws;
  float* rowA = (float*)((char*)d_ws + (size_t)NTOT * D * 2);
  unsigned int* rowM = (unsigned int*)((char*)rowA + (size_t)NTOT * 4);

  prep_kernel<<<2048, 256, 0, stream>>>(feat, X, rowA, rowM);
  gram_kernel<<<NBLK, 256, 0, stream>>>(X, labels, rowA, rowM);
  finalize_kernel<<<1, 256, 0, stream>>>(labels, rowA, rowM, out);
}